// Round 1
// baseline (126.720 us; speedup 1.0000x reference)
//
#include <hip/hip_runtime.h>
#include <hip/hip_bf16.h>
#include <math.h>

// Problem constants (from reference setup_inputs)
constexpr int B_  = 8;
constexpr int CIN = 3;
constexpr int C_  = 64;
constexpr int H_  = 256;
constexpr int W_  = 256;
constexpr int TAPS = 9;   // K*K, K=3

// One block per (b, y) row. 256 threads.
// Phase 0: stage w2 transposed in LDS.
// Phase 1: thread x computes kern[0..8](b, y, x) into LDS.
// Phase 2: wave w handles channels [16w, 16w+16); lane handles x0 = 4*lane.
__global__ __launch_bounds__(256, 4)
void hsa_fused(const float* __restrict__ lr,
               const float* __restrict__ hin,
               const float* __restrict__ w1,
               const float* __restrict__ b1,
               const float* __restrict__ w2,
               const float* __restrict__ b2,
               float* __restrict__ out)
{
    __shared__ float kernS[TAPS][W_];   // 9*256*4 = 9 KB
    __shared__ float w2t[C_][12];       // 64*12*4 = 3 KB (rows 16B-aligned)

    const int tid = threadIdx.x;
    const int blk = blockIdx.x;         // 0 .. B_*H_-1
    const int b = blk / H_;
    const int y = blk % H_;

    // ---- phase 0: transpose w2 [9][64] -> w2t [64][12] ----
    for (int i = tid; i < TAPS * C_; i += 256) {
        const int t = i / C_;
        const int c = i % C_;
        w2t[c][t] = w2[i];
    }
    __syncthreads();

    // ---- phase 1: per-pixel kern ----
    {
        const int x = tid;              // 0..255
        // lr window [cin][row][col], zero-padded
        float win[CIN][3][3];
        #pragma unroll
        for (int ci = 0; ci < CIN; ++ci) {
            #pragma unroll
            for (int r = 0; r < 3; ++r) {
                const int yy = y + r - 1;
                const bool vy = (unsigned)yy < (unsigned)H_;
                const float* row = lr + ((size_t)(b * CIN + ci) * H_ + yy) * W_;
                win[ci][r][0] = (vy && x > 0)       ? row[x - 1] : 0.f;
                win[ci][r][1] = vy                   ? row[x]     : 0.f;
                win[ci][r][2] = (vy && x < W_ - 1)  ? row[x + 1] : 0.f;
            }
        }

        float acc[TAPS];
        #pragma unroll
        for (int t = 0; t < TAPS; ++t) acc[t] = b2[t];

        for (int c = 0; c < C_; ++c) {
            // conv1 (3x3, cin=3) for hidden channel c -- weights are wave-uniform
            float hsum = b1[c];
            const float* wc = w1 + c * 27;
            #pragma unroll
            for (int ci = 0; ci < CIN; ++ci)
                #pragma unroll
                for (int r = 0; r < 3; ++r)
                    #pragma unroll
                    for (int j = 0; j < 3; ++j)
                        hsum = fmaf(wc[(ci * 3 + r) * 3 + j], win[ci][r][j], hsum);
            hsum = fmaxf(hsum, 0.f);    // ReLU

            // 1x1 conv accumulate (w2t row: LDS broadcast)
            const float4 wa = *(const float4*)&w2t[c][0];
            const float4 wb = *(const float4*)&w2t[c][4];
            const float  w8 = w2t[c][8];
            acc[0] = fmaf(wa.x, hsum, acc[0]);
            acc[1] = fmaf(wa.y, hsum, acc[1]);
            acc[2] = fmaf(wa.z, hsum, acc[2]);
            acc[3] = fmaf(wa.w, hsum, acc[3]);
            acc[4] = fmaf(wb.x, hsum, acc[4]);
            acc[5] = fmaf(wb.y, hsum, acc[5]);
            acc[6] = fmaf(wb.z, hsum, acc[6]);
            acc[7] = fmaf(wb.w, hsum, acc[7]);
            acc[8] = fmaf(w8,  hsum, acc[8]);
        }
        #pragma unroll
        for (int t = 0; t < TAPS; ++t) kernS[t][x] = acc[t];
    }
    __syncthreads();

    // ---- phase 2: sim + gate ----
    const int lane = tid & 63;
    const int wav  = tid >> 6;
    const int x0   = lane * 4;

    float4 kt[TAPS];
    #pragma unroll
    for (int t = 0; t < TAPS; ++t) kt[t] = *(const float4*)&kernS[t][x0];

    #pragma unroll 4
    for (int cc = 0; cc < 16; ++cc) {
        const int c = wav * 16 + cc;
        const float* hb = hin + (size_t)(b * C_ + c) * H_ * W_;

        float4 rowv[3];
        float  lft[3], rgt[3];
        #pragma unroll
        for (int r = 0; r < 3; ++r) {
            const int yy = y + r - 1;
            const bool vy = (unsigned)yy < (unsigned)H_;
            float4 m;
            if (vy) m = *(const float4*)(hb + (size_t)yy * W_ + x0);
            else    m = make_float4(0.f, 0.f, 0.f, 0.f);
            rowv[r] = m;
            // column halo via cross-lane shuffle: one wave spans the full row
            float l  = __shfl_up(m.w, 1);
            float rr = __shfl_down(m.x, 1);
            if (lane == 0)  l  = 0.f;   // x = -1 zero pad
            if (lane == 63) rr = 0.f;   // x = 256 zero pad
            lft[r] = l; rgt[r] = rr;
        }

        float sim0 = 0.f, sim1 = 0.f, sim2 = 0.f, sim3 = 0.f;
        #pragma unroll
        for (int r = 0; r < 3; ++r) {
            const float w6_0 = lft[r];
            const float w6_1 = rowv[r].x;
            const float w6_2 = rowv[r].y;
            const float w6_3 = rowv[r].z;
            const float w6_4 = rowv[r].w;
            const float w6_5 = rgt[r];
            {
                const float4 k4 = kt[r * 3 + 0];   // j = 0
                sim0 = fmaf(w6_0, k4.x, sim0);
                sim1 = fmaf(w6_1, k4.y, sim1);
                sim2 = fmaf(w6_2, k4.z, sim2);
                sim3 = fmaf(w6_3, k4.w, sim3);
            }
            {
                const float4 k4 = kt[r * 3 + 1];   // j = 1
                sim0 = fmaf(w6_1, k4.x, sim0);
                sim1 = fmaf(w6_2, k4.y, sim1);
                sim2 = fmaf(w6_3, k4.z, sim2);
                sim3 = fmaf(w6_4, k4.w, sim3);
            }
            {
                const float4 k4 = kt[r * 3 + 2];   // j = 2
                sim0 = fmaf(w6_2, k4.x, sim0);
                sim1 = fmaf(w6_3, k4.y, sim1);
                sim2 = fmaf(w6_4, k4.z, sim2);
                sim3 = fmaf(w6_5, k4.w, sim3);
            }
        }

        float4 o;
        o.x = rowv[1].x * __builtin_amdgcn_rcpf(1.f + __expf(-sim0));
        o.y = rowv[1].y * __builtin_amdgcn_rcpf(1.f + __expf(-sim1));
        o.z = rowv[1].z * __builtin_amdgcn_rcpf(1.f + __expf(-sim2));
        o.w = rowv[1].w * __builtin_amdgcn_rcpf(1.f + __expf(-sim3));
        *(float4*)(out + ((size_t)(b * C_ + c) * H_ + y) * W_ + x0) = o;
    }
}

extern "C" void kernel_launch(void* const* d_in, const int* in_sizes, int n_in,
                              void* d_out, int out_size, void* d_ws, size_t ws_size,
                              hipStream_t stream) {
    const float* lr  = (const float*)d_in[0];  // [8,3,256,256]
    const float* hin = (const float*)d_in[1];  // [8,64,256,256]
    const float* w1  = (const float*)d_in[2];  // [64,3,3,3]
    const float* b1  = (const float*)d_in[3];  // [64]
    const float* w2  = (const float*)d_in[4];  // [9,64,1,1]
    const float* b2  = (const float*)d_in[5];  // [9]
    float* out = (float*)d_out;                // [8,64,256,256]

    dim3 grid(B_ * H_);   // 2048 blocks
    dim3 block(256);
    hipLaunchKernelGGL(hsa_fused, grid, block, 0, stream,
                       lr, hin, w1, b1, w2, b2, out);
}